// Round 1
// baseline (77.008 us; speedup 1.0000x reference)
//
#include <hip/hip_runtime.h>

// Problem constants (from reference)
#define B_ 32
#define C_ 32
#define T_ 8192
#define N_ 256
#define P_ 6

// ---------------------------------------------------------------------------
// Kernel 0: discretize patterns -> per-(p,n) 32-bit char bitmask.
// mask[p][n] bit c set iff patterns[c,p,0,n] == max_c AND sum_c > 0.
// pattern_sums[n] is recovered later as sum_p popcount(mask[p][n]).
// ---------------------------------------------------------------------------
__global__ void k_disc(const float* __restrict__ pat, unsigned* __restrict__ masks) {
    int tid = blockIdx.x * blockDim.x + threadIdx.x;
    if (tid >= P_ * N_) return;
    int p = tid / N_;
    int n = tid - p * N_;
    float maxv = -3.402823466e+38f;
    float sum = 0.0f;
    unsigned mask = 0u;
    #pragma unroll
    for (int c = 0; c < C_; ++c) {
        float v = pat[((size_t)c * P_ + p) * N_ + n];
        sum += v;
        if (v > maxv) { maxv = v; mask = (1u << c); }
        else if (v == maxv) { mask |= (1u << c); }
    }
    if (!(sum > 0.0f)) mask = 0u;
    masks[p * N_ + n] = mask;
}

// ---------------------------------------------------------------------------
// Kernel 1: decode one-hot input (B,C,T,1) -> chars[B][T] (uint8, packed u32).
// chars[b][t] = sum_c c * input[b,c,t]  (exact: one-hot has a single 1.0)
// Each thread handles 4 consecutive t via float4 loads; fully coalesced.
// ---------------------------------------------------------------------------
__global__ void k_chars(const float* __restrict__ inp, unsigned* __restrict__ chars32) {
    int bx = blockIdx.x;                  // [0, B * T/1024)
    int b  = bx >> 3;                     // T/1024 = 8 chunks per batch
    int t  = ((bx & 7) << 10) + (threadIdx.x << 2);
    const float* base = inp + (size_t)b * C_ * T_ + t;
    float ax = 0.f, ay = 0.f, az = 0.f, aw = 0.f;
    #pragma unroll
    for (int c = 0; c < C_; ++c) {
        float4 v = *(const float4*)(base + (size_t)c * T_);
        float fc = (float)c;
        ax += fc * v.x; ay += fc * v.y; az += fc * v.z; aw += fc * v.w;
    }
    unsigned w = ((unsigned)(ax + 0.5f))
               | ((unsigned)(ay + 0.5f) << 8)
               | ((unsigned)(az + 0.5f) << 16)
               | ((unsigned)(aw + 0.5f) << 24);
    chars32[((size_t)b * T_ + t) >> 2] = w;
}

// ---------------------------------------------------------------------------
// Kernel 2: final output. Block = (t-chunk of 1024, n, b), 256 threads,
// each thread produces 4 consecutive t via one float4 store.
// out[b,n,t] = ( (t < T-P+1 ? sum_p bit(mask[p][n], chars[b][t+p]) : 0)
//                == sum_p popcount(mask[p][n]) ) ? 1.0f : 0.0f
// ---------------------------------------------------------------------------
__global__ void k_final(const unsigned char* __restrict__ chars,
                        const unsigned* __restrict__ masks,
                        float* __restrict__ out) {
    __shared__ unsigned s32[258];         // 1024 chars + 8 halo bytes
    int tc  = blockIdx.x;                 // 0..7
    int n   = blockIdx.y;                 // 0..255
    int b   = blockIdx.z;                 // 0..31
    int tid = threadIdx.x;
    int t0  = tc << 10;

    const unsigned* csrc = (const unsigned*)(chars + (size_t)b * T_ + t0);
    s32[tid] = csrc[tid];
    if (tid < 2) {
        unsigned v = 0u;
        int gt = t0 + 1024 + tid * 4;     // byte index into chars[b][*]
        if (gt < T_) v = csrc[256 + tid];
        s32[256 + tid] = v;
    }

    // Block-uniform (n from blockIdx) -> scalar loads
    unsigned m0 = masks[0 * N_ + n], m1 = masks[1 * N_ + n], m2 = masks[2 * N_ + n];
    unsigned m3 = masks[3 * N_ + n], m4 = masks[4 * N_ + n], m5 = masks[5 * N_ + n];
    int psum = __popc(m0) + __popc(m1) + __popc(m2)
             + __popc(m3) + __popc(m4) + __popc(m5);

    __syncthreads();

    unsigned w0 = s32[tid], w1 = s32[tid + 1], w2 = s32[tid + 2];
    unsigned by[12];
    #pragma unroll
    for (int i = 0; i < 4; ++i) {
        by[i]     = (w0 >> (i * 8)) & 0xffu;
        by[i + 4] = (w1 >> (i * 8)) & 0xffu;
        by[i + 8] = (w2 >> (i * 8)) & 0xffu;
    }

    float res[4];
    #pragma unroll
    for (int j = 0; j < 4; ++j) {
        int t = t0 + (tid << 2) + j;
        int cnt = (int)((m0 >> by[j    ]) & 1u) + (int)((m1 >> by[j + 1]) & 1u)
                + (int)((m2 >> by[j + 2]) & 1u) + (int)((m3 >> by[j + 3]) & 1u)
                + (int)((m4 >> by[j + 4]) & 1u) + (int)((m5 >> by[j + 5]) & 1u);
        int eff = (t < T_ - P_ + 1) ? cnt : 0;   // pad region: conv == 0
        res[j] = (eff == psum) ? 1.0f : 0.0f;
    }

    float4 r; r.x = res[0]; r.y = res[1]; r.z = res[2]; r.w = res[3];
    *(float4*)(out + ((size_t)(b * N_ + n)) * T_ + t0 + (tid << 2)) = r;
}

// ---------------------------------------------------------------------------
extern "C" void kernel_launch(void* const* d_in, const int* in_sizes, int n_in,
                              void* d_out, int out_size, void* d_ws, size_t ws_size,
                              hipStream_t stream) {
    const float* input_   = (const float*)d_in[0];   // (B,C,T,1) one-hot fp32
    const float* patterns = (const float*)d_in[1];   // (C,P,1,N) fp32
    float* out = (float*)d_out;                      // (B,N,T,1) fp32

    // Workspace layout: [0, 6144) masks (P*N u32); [8192, 8192+B*T) chars u8
    unsigned*      masks = (unsigned*)d_ws;
    unsigned char* chars = (unsigned char*)d_ws + 8192;

    hipLaunchKernelGGL(k_disc, dim3((P_ * N_ + 255) / 256), dim3(256), 0, stream,
                       patterns, masks);
    hipLaunchKernelGGL(k_chars, dim3(B_ * (T_ / 1024)), dim3(256), 0, stream,
                       input_, (unsigned*)chars);
    hipLaunchKernelGGL(k_final, dim3(T_ / 1024, N_, B_), dim3(256), 0, stream,
                       chars, masks, out);
}